// Round 6
// baseline (706.070 us; speedup 1.0000x reference)
//
#include <hip/hip_runtime.h>

static constexpr int DIM   = 256;
static constexpr int NCODE = 8192;
static constexpr int NROWS = 16384;

typedef __bf16 bf16x8 __attribute__((ext_vector_type(8)));
typedef float  f32x4  __attribute__((ext_vector_type(4)));

// ---------------------------------------------------------------------------
// top2 helpers (validated rounds 1-4)
// ---------------------------------------------------------------------------
__device__ __forceinline__ void top2_insert(float& v0, int& i0, float& v1, int& i1,
                                            float s, int si) {
    if (s < v0) { v1 = v0; i1 = i0; v0 = s; i0 = si; }
    else if (s < v1) { v1 = s; i1 = si; }
}
__device__ __forceinline__ void top2_merge(float& v0, int& i0, float& v1, int& i1,
                                           float b0, int bi0, float b1, int bi1) {
    if (b0 < v0) {
        if (b1 < v0) { v0 = b0; i0 = bi0; v1 = b1; i1 = bi1; }
        else         { v1 = v0; i1 = i0;  v0 = b0; i0 = bi0; }
    } else if (b0 < v1) { v1 = b0; i1 = bi0; }
}

// ---------------------------------------------------------------------------
// P0 fused prep: [0,2048) cvt_x | [2048,2560) cvt_e | [2560,2592) e2 (exact)
// ---------------------------------------------------------------------------
__global__ __launch_bounds__(256) void prep_kernel(
    const float* __restrict__ x, const float* __restrict__ embed,
    ushort* __restrict__ xb, ushort* __restrict__ eb16,
    float* __restrict__ ebT32, float* __restrict__ e2)
{
    __shared__ float tile[64][65];
    const int b = blockIdx.x;
    const int t = threadIdx.x;

    if (b < 2048) {                      // ---- cvt_x ----
        int i = b * 256 + t;
        const float4* xp = (const float4*)x + (size_t)i * 2;
        float4 a = xp[0], v = xp[1];
        bf16x8 o;
        o[0] = (__bf16)a.x; o[1] = (__bf16)a.y; o[2] = (__bf16)a.z; o[3] = (__bf16)a.w;
        o[4] = (__bf16)v.x; o[5] = (__bf16)v.y; o[6] = (__bf16)v.z; o[7] = (__bf16)v.w;
        ((bf16x8*)xb)[i] = o;
    } else if (b < 2560) {               // ---- cvt_e ----
        const int eb = b - 2048;
        const int c00 = (eb & 127) * 64;
        const int k0  = (eb >> 7) * 64;
        const int tc  = t & 63, tr4 = t >> 6;
        #pragma unroll
        for (int i = 0; i < 16; ++i) {
            int r = i * 4 + tr4;
            tile[r][tc] = embed[(size_t)(k0 + r) * NCODE + c00 + tc];
        }
        __syncthreads();
        const int cl = t >> 2;
        const int kq = t & 3;
        float vals[16];
        #pragma unroll
        for (int j = 0; j < 16; ++j) vals[j] = tile[kq * 16 + j][cl];
        float* d32 = ebT32 + (size_t)(c00 + cl) * DIM + k0 + kq * 16;
        #pragma unroll
        for (int j = 0; j < 4; ++j)
            *(float4*)(d32 + j * 4) = make_float4(vals[j*4], vals[j*4+1],
                                                  vals[j*4+2], vals[j*4+3]);
        bf16x8 h0, h1;
        #pragma unroll
        for (int j = 0; j < 8; ++j) { h0[j] = (__bf16)vals[j]; h1[j] = (__bf16)vals[8 + j]; }
        ushort* d16 = eb16 + (size_t)(c00 + cl) * DIM + k0 + kq * 16;
        *(bf16x8*)d16 = h0;
        *(bf16x8*)(d16 + 8) = h1;
    } else {                             // ---- e2 (exact serial chain) ----
        int j = (b - 2560) * 256 + t;
        float s = 0.f;
        for (int k = 0; k < DIM; ++k) {
            float v = embed[(size_t)k * NCODE + j];
            s = __fadd_rn(s, __fmul_rn(v, v));
        }
        e2[j] = s;
    }
}

// ---------------------------------------------------------------------------
// K1: B-stationary persistent GEMM + per-row top2 per 128-code chunk.
// Grid = 256 (64 chunks x 4 rowgroups), 8 waves as 2(row) x 4(code).
// B codes x K256 staged to LDS once, then HOISTED TO REGISTERS (bq[2][8],
// 64 VGPR) -> per-tt LDS traffic is A-frags only (128 KB/tt).
// LDS layout [kg][slot] with slot = (row ^ kg) & mask: 2-way max on both
// stage-writes and frag-reads (free).
// MFMA operands SWAPPED: mfma(code_frag, xrow_frag) -> C[code][xrow]; each
// lane then holds 8 codes for one xrow -> top2 = 8 in-lane inserts + 2
// shuffle-merge steps (xor 16/32).
// Output: compact 8B scratch [chunk][row]: {v0 f32, i0|i1<<13|dq<<26}.
// ---------------------------------------------------------------------------
__global__ __launch_bounds__(512, 1) void gemm_top2_kernel(
    const ushort* __restrict__ xb,   // [NROWS][256] bf16
    const ushort* __restrict__ eb,   // [NCODE][256] bf16 (embed^T)
    const float* __restrict__ e2g,   // [NCODE]
    uint2* __restrict__ scratch)     // [64 chunks][16384 rows]
{
    __shared__ ushort Bs[32768];       // [kg 32][slot 128] 16B units (64 KB)
    __shared__ ushort As[2][16384];    // [kg 32][slot 64]  16B units (2x32 KB)
    __shared__ uint4  ldsM[4][64];     // cross-wave top2 merge (4 KB)

    const int t       = threadIdx.x;
    const int chunk   = blockIdx.x >> 2;
    const int rg      = blockIdx.x & 3;
    const int c0      = chunk * 128;
    const int rowbase = rg * 4096;

    const int wid = t >> 6, lane = t & 63;
    const int wr  = wid >> 2, wc = wid & 3;    // 2 x 4 wave grid
    const int lr  = lane & 15, g = lane >> 4;

    // ---- prologue: linear global loads, swizzled LDS writes ----
    {
        const char* bb = (const char*)(eb + (size_t)c0 * DIM);
        uint4 breg[8];
        #pragma unroll
        for (int i = 0; i < 8; ++i)
            breg[i] = *(const uint4*)(bb + i * 8192 + t * 16);
        const char* ab = (const char*)(xb + (size_t)rowbase * DIM);
        uint4 areg[4];
        #pragma unroll
        for (int i = 0; i < 4; ++i)
            areg[i] = *(const uint4*)(ab + i * 8192 + t * 16);
        #pragma unroll
        for (int i = 0; i < 8; ++i) {
            int o = i * 8192 + t * 16;
            int code = o >> 9, kg = (o >> 4) & 31;
            *(uint4*)((char*)Bs + kg * 2048 + (((code ^ kg) & 127) << 4)) = breg[i];
        }
        #pragma unroll
        for (int i = 0; i < 4; ++i) {
            int o = i * 8192 + t * 16;
            int row = o >> 9, kg = (o >> 4) & 31;
            *(uint4*)((char*)As[0] + kg * 1024 + (((row ^ kg) & 63) << 4)) = areg[i];
        }
    }
    __syncthreads();

    // ---- hoist B fragments to registers: bq[cf][ks] (fully static indices)
    bf16x8 bq[2][8];
    #pragma unroll
    for (int cf = 0; cf < 2; ++cf) {
        #pragma unroll
        for (int ks = 0; ks < 8; ++ks) {
            int code = wc * 32 + cf * 16 + lr;
            int kg   = ks * 4 + g;
            bq[cf][ks] = *(const bf16x8*)((char*)Bs + kg * 2048 +
                                          (((code ^ kg) & 127) << 4));
        }
    }

    // e2 for this lane's 8 codes: code = c0 + wc*32 + cf*16 + g*4 + reg
    float e2v[2][4];
    #pragma unroll
    for (int cf = 0; cf < 2; ++cf)
        #pragma unroll
        for (int reg = 0; reg < 4; ++reg)
            e2v[cf][reg] = e2g[c0 + wc * 32 + cf * 16 + g * 4 + reg];

    int cur = 0;
    for (int tt = 0; tt < 64; ++tt) {
        // issue next A-tile loads early (linear, coalesced)
        uint4 nreg[4];
        if (tt < 63) {
            const char* an = (const char*)(xb + (size_t)(rowbase + (tt + 1) * 64) * DIM);
            #pragma unroll
            for (int i = 0; i < 4; ++i)
                nreg[i] = *(const uint4*)(an + i * 8192 + t * 16);
        }

        // ---- compute: A-frag reads only; 32 MFMA / wave ----
        f32x4 acc[2][2];                 // [cf][rf]
        #pragma unroll
        for (int cf = 0; cf < 2; ++cf)
            #pragma unroll
            for (int rf = 0; rf < 2; ++rf) acc[cf][rf] = (f32x4){0.f, 0.f, 0.f, 0.f};

        const char* Ab = (const char*)As[cur];
        #pragma unroll
        for (int ks = 0; ks < 8; ++ks) {
            bf16x8 af[2];
            #pragma unroll
            for (int rf = 0; rf < 2; ++rf) {
                int row = wr * 32 + rf * 16 + lr;
                int kg  = ks * 4 + g;
                af[rf] = *(const bf16x8*)(Ab + kg * 1024 + (((row ^ kg) & 63) << 4));
            }
            #pragma unroll
            for (int cf = 0; cf < 2; ++cf)
                #pragma unroll
                for (int rf = 0; rf < 2; ++rf)
                    acc[cf][rf] = __builtin_amdgcn_mfma_f32_16x16x32_bf16(
                        bq[cf][ks], af[rf], acc[cf][rf], 0, 0, 0);
        }

        // ---- epilogue: per-lane top2 over its 8 codes, merge across g ----
        #pragma unroll
        for (int rf = 0; rf < 2; ++rf) {
            float v0 = __builtin_inff(), v1 = __builtin_inff();
            int   i0 = -1, i1 = -1;
            #pragma unroll
            for (int cf = 0; cf < 2; ++cf) {
                #pragma unroll
                for (int reg = 0; reg < 4; ++reg) {
                    float sv = __builtin_fmaf(-2.f, acc[cf][rf][reg], e2v[cf][reg]);
                    top2_insert(v0, i0, v1, i1, sv,
                                c0 + wc * 32 + cf * 16 + g * 4 + reg);
                }
            }
            #pragma unroll
            for (int m = 16; m <= 32; m <<= 1) {
                float b0 = __shfl_xor(v0, m), b1 = __shfl_xor(v1, m);
                int  bi0 = __shfl_xor(i0, m), bi1 = __shfl_xor(i1, m);
                top2_merge(v0, i0, v1, i1, b0, bi0, b1, bi1);
            }
            if (g == 0)
                ldsM[wc][wr * 32 + rf * 16 + lr] =
                    make_uint4(__float_as_uint(v0), (unsigned)i0,
                               __float_as_uint(v1), (unsigned)i1);
        }
        __syncthreads();                 // ldsM ready; As[cur] reads done

        if (t < 64) {                    // merge 4 code-waves -> compact entry
            uint4 E = ldsM[0][t];
            float v0 = __uint_as_float(E.x), v1 = __uint_as_float(E.z);
            int   i0 = (int)E.y,             i1 = (int)E.w;
            #pragma unroll
            for (int k = 1; k < 4; ++k) {
                uint4 F = ldsM[k][t];
                top2_merge(v0, i0, v1, i1, __uint_as_float(F.x), (int)F.y,
                           __uint_as_float(F.z), (int)F.w);
            }
            float delta = v1 - v0;
            unsigned dq = (unsigned)min(63, (int)(delta * 32.f));  // round DOWN
            unsigned w2 = (unsigned)i0 | ((unsigned)i1 << 13) | (dq << 26);
            scratch[(size_t)chunk * NROWS + rowbase + tt * 64 + t] =
                make_uint2(__float_as_uint(v0), w2);
        }

        if (tt < 63) {                   // publish next A tile (swizzled writes)
            #pragma unroll
            for (int i = 0; i < 4; ++i) {
                int o = i * 8192 + t * 16;
                int row = o >> 9, kg = (o >> 4) & 31;
                *(uint4*)((char*)As[cur ^ 1] + kg * 1024 +
                          (((row ^ kg) & 63) << 4)) = nreg[i];
            }
        }
        __syncthreads();                 // As[next] ready; ldsM reusable
        cur ^= 1;
    }
}

// ---------------------------------------------------------------------------
// K2 fused finalize: band capture + exact fp32 rescore + gather/diff/ind.
// (verbatim from round 4 — validated)
// ---------------------------------------------------------------------------
__global__ __launch_bounds__(256) void finalize_kernel(
    const uint2* __restrict__ scratch, const float* __restrict__ x,
    const float* __restrict__ ebT32, const float* __restrict__ e2g,
    float* __restrict__ quant, float* __restrict__ diff, float* __restrict__ ind)
{
    __shared__ float    wmin[4][64];
    __shared__ float    thr[64];
    __shared__ unsigned cnt[64];
    __shared__ unsigned cand[64][12];
    __shared__ unsigned bestIdx[64];
    __shared__ float    partial[4];

    const int t  = threadIdx.x;
    const int w  = t >> 6, l = t & 63;
    const int R0 = blockIdx.x * 64;

    if (t < 64) cnt[t] = 0;

    // pass A: per-row global approx min over 64 chunks (16 per wave)
    float m = __builtin_inff();
    #pragma unroll 4
    for (int i = 0; i < 16; ++i) {
        uint2 e = scratch[(size_t)(w * 16 + i) * NROWS + R0 + l];
        m = fminf(m, __uint_as_float(e.x));
    }
    wmin[w][l] = m;
    __syncthreads();
    if (t < 64)
        thr[t] = fminf(fminf(wmin[0][t], wmin[1][t]),
                       fminf(wmin[2][t], wmin[3][t])) + 1.0f;
    __syncthreads();

    // pass B: collect in-band candidates (v1 reconstructed from below)
    const float th = thr[l];
    for (int i = 0; i < 16; ++i) {
        uint2 e = scratch[(size_t)(w * 16 + i) * NROWS + R0 + l];
        float v0 = __uint_as_float(e.x);
        if (v0 <= th) {
            unsigned s = atomicAdd(&cnt[l], 1u);
            if (s < 12) cand[l][s] = e.y & 8191u;
        }
        float v1lo = v0 + (float)((e.y >> 26) & 63u) * 0.03125f;
        if (v1lo <= th) {
            unsigned s = atomicAdd(&cnt[l], 1u);
            if (s < 12) cand[l][s] = (e.y >> 13) & 8191u;
        }
    }
    __syncthreads();

    // rescore: lane = rl*4 + slot; exact round-1 fp32 chain
    const int rl = l >> 2, slot = l & 3;
    const int rrow = R0 + w * 16 + rl;
    const int cn = min((int)cnt[w * 16 + rl], 12);
    float best = __builtin_inff();
    unsigned bidx = 0xFFFFFFFFu;
    for (int s = slot; s < cn; s += 4) {
        unsigned idx = cand[w * 16 + rl][s];
        const float* xr = x + (size_t)rrow * DIM;
        const float* er = ebT32 + (size_t)idx * DIM;
        float f2 = 0.f, dot = 0.f;
        for (int k = 0; k < DIM; ++k) {
            float xv = xr[k];
            f2  = __fadd_rn(f2, __fmul_rn(xv, xv));
            dot = __builtin_fmaf(xv, er[k], dot);
        }
        float d = __fadd_rn(__builtin_fmaf(-2.f, dot, f2), e2g[idx]);
        if (d < best || (d == best && idx < bidx)) { best = d; bidx = idx; }
    }
    #pragma unroll
    for (int mm = 1; mm < 4; mm <<= 1) {
        float    od = __shfl_xor(best, mm);
        unsigned oi = (unsigned)__shfl_xor((int)bidx, mm);
        if (od < best || (od == best && oi < bidx)) { best = od; bidx = oi; }
    }
    if (slot == 0) bestIdx[w * 16 + rl] = bidx;
    __syncthreads();

    // output: gather + straight-through + diff accumulation
    float accv = 0.f;
    for (int r = 0; r < 64; ++r) {
        const int row2 = R0 + r;
        const unsigned idx = bestIdx[r];
        float xv = x[(size_t)row2 * DIM + t];
        float q  = ebT32[(size_t)idx * DIM + t];
        float dq = __fsub_rn(q, xv);
        quant[(size_t)row2 * DIM + t] = __fadd_rn(xv, dq);
        accv += __fmul_rn(dq, dq);
    }
    #pragma unroll
    for (int off = 32; off >= 1; off >>= 1) accv += __shfl_down(accv, off);
    if (l == 0) partial[w] = accv;
    __syncthreads();
    if (t == 0) {
        float s = (partial[0] + partial[1]) + (partial[2] + partial[3]);
        atomicAdd(diff, s * (1.25f / 4194304.f));
    }
    if (t < 64) ind[R0 + t] = (float)bestIdx[t];
}

// ---------------------------------------------------------------------------
extern "C" void kernel_launch(void* const* d_in, const int* in_sizes, int n_in,
                              void* d_out, int out_size, void* d_ws, size_t ws_size,
                              hipStream_t stream)
{
    const float* x     = (const float*)d_in[0];   // [16384,256]
    const float* embed = (const float*)d_in[1];   // [256,8192]

    float* out   = (float*)d_out;
    float* quant = out;
    float* diff  = out + 4194304;
    float* ind   = out + 4194305;

    // xb (bf16 x, 8 MB) overlays the quantize region: written by prep, read
    // only by gemm, overwritten by finalize (stream-ordered) -> safe.
    ushort* xb = (ushort*)quant;

    // workspace (20.1 MB)
    char* w = (char*)d_ws;
    ushort* eb16    = (ushort*)(w);               //  4 MB
    float*  ebT32   = (float*) (w + 4194304);     //  8 MB
    float*  e2      = (float*) (w + 12582912);    // 32 KB
    uint2*  scratch = (uint2*) (w + 12615680);    //  8 MB  [64][16384]

    prep_kernel<<<2592, 256, 0, stream>>>(x, embed, xb, eb16, ebT32, e2);
    gemm_top2_kernel<<<256, 512, 0, stream>>>(xb, eb16, e2, scratch);
    hipMemsetAsync(diff, 0, sizeof(float), stream);
    finalize_kernel<<<256, 256, 0, stream>>>(scratch, x, ebT32, e2, quant, diff, ind);
}

// Round 7
// 669.127 us; speedup vs baseline: 1.0552x; 1.0552x over previous
//
#include <hip/hip_runtime.h>

static constexpr int DIM   = 256;
static constexpr int NCODE = 8192;
static constexpr int NROWS = 16384;

typedef __bf16 bf16x8 __attribute__((ext_vector_type(8)));
typedef float  f32x4  __attribute__((ext_vector_type(4)));

// ---------------------------------------------------------------------------
// top2 helpers (validated rounds 1-6)
// ---------------------------------------------------------------------------
__device__ __forceinline__ void top2_insert(float& v0, int& i0, float& v1, int& i1,
                                            float s, int si) {
    if (s < v0) { v1 = v0; i1 = i0; v0 = s; i0 = si; }
    else if (s < v1) { v1 = s; i1 = si; }
}
__device__ __forceinline__ void top2_merge(float& v0, int& i0, float& v1, int& i1,
                                           float b0, int bi0, float b1, int bi1) {
    if (b0 < v0) {
        if (b1 < v0) { v0 = b0; i0 = bi0; v1 = b1; i1 = bi1; }
        else         { v1 = v0; i1 = i0;  v0 = b0; i0 = bi0; }
    } else if (b0 < v1) { v1 = b0; i1 = bi0; }
}

// ---------------------------------------------------------------------------
// P0 fused prep: [0,2048) cvt_x | [2048,2560) cvt_e (bf16 transpose only)
//                | [2560,2592) e2 (exact serial chain)
// ---------------------------------------------------------------------------
__global__ __launch_bounds__(256) void prep_kernel(
    const float* __restrict__ x, const float* __restrict__ embed,
    ushort* __restrict__ xb, ushort* __restrict__ eb16, float* __restrict__ e2)
{
    __shared__ float tile[64][65];
    const int b = blockIdx.x;
    const int t = threadIdx.x;

    if (b < 2048) {                      // ---- cvt_x ----
        int i = b * 256 + t;
        const float4* xp = (const float4*)x + (size_t)i * 2;
        float4 a = xp[0], v = xp[1];
        bf16x8 o;
        o[0] = (__bf16)a.x; o[1] = (__bf16)a.y; o[2] = (__bf16)a.z; o[3] = (__bf16)a.w;
        o[4] = (__bf16)v.x; o[5] = (__bf16)v.y; o[6] = (__bf16)v.z; o[7] = (__bf16)v.w;
        ((bf16x8*)xb)[i] = o;
    } else if (b < 2560) {               // ---- cvt_e (transpose + bf16) ----
        const int eb = b - 2048;
        const int c00 = (eb & 127) * 64;
        const int k0  = (eb >> 7) * 64;
        const int tc  = t & 63, tr4 = t >> 6;
        #pragma unroll
        for (int i = 0; i < 16; ++i) {
            int r = i * 4 + tr4;
            tile[r][tc] = embed[(size_t)(k0 + r) * NCODE + c00 + tc];
        }
        __syncthreads();
        const int cl = t >> 2;
        const int kq = t & 3;
        float vals[16];
        #pragma unroll
        for (int j = 0; j < 16; ++j) vals[j] = tile[kq * 16 + j][cl];
        bf16x8 h0, h1;
        #pragma unroll
        for (int j = 0; j < 8; ++j) { h0[j] = (__bf16)vals[j]; h1[j] = (__bf16)vals[8 + j]; }
        ushort* d16 = eb16 + (size_t)(c00 + cl) * DIM + k0 + kq * 16;
        *(bf16x8*)d16 = h0;
        *(bf16x8*)(d16 + 8) = h1;
    } else {                             // ---- e2 (exact serial chain) ----
        int j = (b - 2560) * 256 + t;
        float s = 0.f;
        for (int k = 0; k < DIM; ++k) {
            float v = embed[(size_t)k * NCODE + j];
            s = __fadd_rn(s, __fmul_rn(v, v));
        }
        e2[j] = s;
    }
}

// ---------------------------------------------------------------------------
// K1: barrier-free wave-independent GEMM + per-row top2 per 64-code chunk.
// Grid = 512 blocks (64 code-pairs x 8 rowgroups) = 2 blocks/CU; 4 waves as
// 2(row wr) x 2(codehalf wc). ONE barrier total (B-stage). Then each wave:
//   - B panel (64 codes x K256) resident in bq[4][8] registers (128 VGPR)
//   - A fragments read DIRECTLY from global (bf16x8; 16x64B segments/load;
//     L1/L2-resident, rowgroup shared by the 64 same-XCD blocks via %8 dispatch)
//   - 64 MFMA per 64-row step, swapped operands -> C[code][xrow]
//   - in-lane top2 over 16 codes + 2 shuffle-merge steps, scratch store
// No __syncthreads in the loop; no LDS traffic in the loop; loads pipeline
// freely across iterations.
// B LDS layout: [kg 32][code' 128] 16B units, code' = (code+kg)&127
//   (stage-writes 2-way, hoist-reads 2-way: conflict-free both sides).
// Scratch: [128 chunk-cols][16384 rows] x 8B {v0 f32, i0|i1<<13|dq<<26}.
// ---------------------------------------------------------------------------
__global__ __launch_bounds__(256, 2) void gemm_top2_kernel(
    const ushort* __restrict__ xb,   // [NROWS][256] bf16
    const ushort* __restrict__ eb,   // [NCODE][256] bf16 (embed^T)
    const float* __restrict__ e2g,   // [NCODE]
    uint2* __restrict__ scratch)     // [128][16384]
{
    __shared__ ushort Bs[32768];     // 64 KB

    const int t       = threadIdx.x;
    const int cpair   = blockIdx.x >> 3;     // 0..63  (128 codes)
    const int rg      = blockIdx.x & 7;      // 0..7   (2048 rows)
    const int c0      = cpair * 128;
    const int rowbase = rg * 2048;

    const int wid = t >> 6, lane = t & 63;
    const int wr  = wid >> 1, wc = wid & 1;  // 2 x 2 wave grid
    const int lr  = lane & 15, g = lane >> 4;

    // ---- stage B once: linear global loads, swizzled LDS writes ----
    {
        const char* bb = (const char*)(eb + (size_t)c0 * DIM);
        uint4 breg[16];
        #pragma unroll
        for (int i = 0; i < 16; ++i)
            breg[i] = *(const uint4*)(bb + i * 4096 + t * 16);
        #pragma unroll
        for (int i = 0; i < 16; ++i) {
            int o = i * 4096 + t * 16;
            int code = o >> 9, kg = (o >> 4) & 31;
            *(uint4*)((char*)Bs + kg * 2048 + (((code + kg) & 127) << 4)) = breg[i];
        }
    }
    __syncthreads();                 // the ONLY barrier

    // ---- hoist B panel to registers: bq[cf][ks] (static indices) ----
    bf16x8 bq[4][8];
    #pragma unroll
    for (int cf = 0; cf < 4; ++cf) {
        #pragma unroll
        for (int ks = 0; ks < 8; ++ks) {
            int codeL = wc * 64 + cf * 16 + lr;
            int kg    = ks * 4 + g;
            bq[cf][ks] = *(const bf16x8*)((char*)Bs + kg * 2048 +
                                          (((codeL + kg) & 127) << 4));
        }
    }

    // e2 for this lane's 16 codes: code = c0 + wc*64 + cf*16 + g*4 + reg
    float e2v[4][4];
    #pragma unroll
    for (int cf = 0; cf < 4; ++cf)
        #pragma unroll
        for (int reg = 0; reg < 4; ++reg)
            e2v[cf][reg] = e2g[c0 + wc * 64 + cf * 16 + g * 4 + reg];

    const char* ab    = (const char*)xb;
    const int   ccol  = cpair * 2 + wc;      // scratch column

    for (int tt = 0; tt < 32; ++tt) {
        const int row0 = rowbase + tt * 64 + wr * 32;

        f32x4 acc[4][2];                     // [cf][rf]
        #pragma unroll
        for (int cf = 0; cf < 4; ++cf)
            #pragma unroll
            for (int rf = 0; rf < 2; ++rf) acc[cf][rf] = (f32x4){0.f, 0.f, 0.f, 0.f};

        #pragma unroll
        for (int half = 0; half < 2; ++half) {
            bf16x8 af[4][2];                 // 4 k-steps x 2 row-frags (32 VGPR)
            #pragma unroll
            for (int k4 = 0; k4 < 4; ++k4)
                #pragma unroll
                for (int rf = 0; rf < 2; ++rf)
                    af[k4][rf] = *(const bf16x8*)(ab +
                        (size_t)(row0 + rf * 16 + lr) * 512 +
                        (half * 4 + k4) * 64 + g * 16);
            #pragma unroll
            for (int k4 = 0; k4 < 4; ++k4)
                #pragma unroll
                for (int cf = 0; cf < 4; ++cf)
                    #pragma unroll
                    for (int rf = 0; rf < 2; ++rf)
                        acc[cf][rf] = __builtin_amdgcn_mfma_f32_16x16x32_bf16(
                            bq[cf][half * 4 + k4], af[k4][rf], acc[cf][rf], 0, 0, 0);
        }

        // ---- epilogue: in-lane top2 over 16 codes, merge across g ----
        #pragma unroll
        for (int rf = 0; rf < 2; ++rf) {
            float v0 = __builtin_inff(), v1 = __builtin_inff();
            int   i0 = -1, i1 = -1;
            #pragma unroll
            for (int cf = 0; cf < 4; ++cf) {
                #pragma unroll
                for (int reg = 0; reg < 4; ++reg) {
                    float sv = __builtin_fmaf(-2.f, acc[cf][rf][reg], e2v[cf][reg]);
                    top2_insert(v0, i0, v1, i1, sv,
                                c0 + wc * 64 + cf * 16 + g * 4 + reg);
                }
            }
            #pragma unroll
            for (int m = 16; m <= 32; m <<= 1) {
                float b0 = __shfl_xor(v0, m), b1 = __shfl_xor(v1, m);
                int  bi0 = __shfl_xor(i0, m), bi1 = __shfl_xor(i1, m);
                top2_merge(v0, i0, v1, i1, b0, bi0, b1, bi1);
            }
            if (g == 0) {
                float delta = v1 - v0;
                unsigned dq = (unsigned)min(63, (int)(delta * 32.f));  // round DOWN
                unsigned w2 = (unsigned)i0 | ((unsigned)i1 << 13) | (dq << 26);
                scratch[(size_t)ccol * NROWS + row0 + rf * 16 + lr] =
                    make_uint2(__float_as_uint(v0), w2);
            }
        }
    }
}

// ---------------------------------------------------------------------------
// K2 fused finalize: band capture + exact fp32 rescore + gather/diff/ind.
// 128 chunk-columns now; rescore & gather read embed COLUMN-wise
// (R1-validated pattern; values bit-identical to ebT32 reads).
// ---------------------------------------------------------------------------
__global__ __launch_bounds__(256) void finalize_kernel(
    const uint2* __restrict__ scratch, const float* __restrict__ x,
    const float* __restrict__ embed, const float* __restrict__ e2g,
    float* __restrict__ quant, float* __restrict__ diff, float* __restrict__ ind)
{
    __shared__ float    wmin[4][64];
    __shared__ float    thr[64];
    __shared__ unsigned cnt[64];
    __shared__ unsigned cand[64][12];
    __shared__ unsigned bestIdx[64];
    __shared__ float    partial[4];

    const int t  = threadIdx.x;
    const int w  = t >> 6, l = t & 63;
    const int R0 = blockIdx.x * 64;

    if (t < 64) cnt[t] = 0;

    // pass A: per-row approx min over 128 chunk-cols (32 per wave)
    float m = __builtin_inff();
    #pragma unroll 4
    for (int i = 0; i < 32; ++i) {
        uint2 e = scratch[(size_t)(w * 32 + i) * NROWS + R0 + l];
        m = fminf(m, __uint_as_float(e.x));
    }
    wmin[w][l] = m;
    __syncthreads();
    if (t < 64)
        thr[t] = fminf(fminf(wmin[0][t], wmin[1][t]),
                       fminf(wmin[2][t], wmin[3][t])) + 1.0f;
    __syncthreads();

    // pass B: collect in-band candidates (v1 reconstructed from below)
    const float th = thr[l];
    for (int i = 0; i < 32; ++i) {
        uint2 e = scratch[(size_t)(w * 32 + i) * NROWS + R0 + l];
        float v0 = __uint_as_float(e.x);
        if (v0 <= th) {
            unsigned s = atomicAdd(&cnt[l], 1u);
            if (s < 12) cand[l][s] = e.y & 8191u;
        }
        float v1lo = v0 + (float)((e.y >> 26) & 63u) * 0.03125f;
        if (v1lo <= th) {
            unsigned s = atomicAdd(&cnt[l], 1u);
            if (s < 12) cand[l][s] = (e.y >> 13) & 8191u;
        }
    }
    __syncthreads();

    // rescore: lane = rl*4 + slot; exact round-1 fp32 chain (embed columns)
    const int rl = l >> 2, slot = l & 3;
    const int rrow = R0 + w * 16 + rl;
    const int cn = min((int)cnt[w * 16 + rl], 12);
    float best = __builtin_inff();
    unsigned bidx = 0xFFFFFFFFu;
    for (int s = slot; s < cn; s += 4) {
        unsigned idx = cand[w * 16 + rl][s];
        const float* xr = x + (size_t)rrow * DIM;
        float f2 = 0.f, dot = 0.f;
        for (int k = 0; k < DIM; ++k) {
            float xv = xr[k];
            f2  = __fadd_rn(f2, __fmul_rn(xv, xv));
            dot = __builtin_fmaf(xv, embed[(size_t)k * NCODE + idx], dot);
        }
        float d = __fadd_rn(__builtin_fmaf(-2.f, dot, f2), e2g[idx]);
        if (d < best || (d == best && idx < bidx)) { best = d; bidx = idx; }
    }
    #pragma unroll
    for (int mm = 1; mm < 4; mm <<= 1) {
        float    od = __shfl_xor(best, mm);
        unsigned oi = (unsigned)__shfl_xor((int)bidx, mm);
        if (od < best || (od == best && oi < bidx)) { best = od; bidx = oi; }
    }
    if (slot == 0) bestIdx[w * 16 + rl] = bidx;
    __syncthreads();

    // output: gather (embed columns) + straight-through + diff accumulation
    float accv = 0.f;
    for (int r = 0; r < 64; ++r) {
        const int row2 = R0 + r;
        const unsigned idx = bestIdx[r];
        float xv = x[(size_t)row2 * DIM + t];
        float q  = embed[(size_t)t * NCODE + idx];
        float dq = __fsub_rn(q, xv);
        quant[(size_t)row2 * DIM + t] = __fadd_rn(xv, dq);
        accv += __fmul_rn(dq, dq);
    }
    #pragma unroll
    for (int off = 32; off >= 1; off >>= 1) accv += __shfl_down(accv, off);
    if (l == 0) partial[w] = accv;
    __syncthreads();
    if (t == 0) {
        float s = (partial[0] + partial[1]) + (partial[2] + partial[3]);
        atomicAdd(diff, s * (1.25f / 4194304.f));
    }
    if (t < 64) ind[R0 + t] = (float)bestIdx[t];
}

// ---------------------------------------------------------------------------
extern "C" void kernel_launch(void* const* d_in, const int* in_sizes, int n_in,
                              void* d_out, int out_size, void* d_ws, size_t ws_size,
                              hipStream_t stream)
{
    const float* x     = (const float*)d_in[0];   // [16384,256]
    const float* embed = (const float*)d_in[1];   // [256,8192]

    float* out   = (float*)d_out;
    float* quant = out;
    float* diff  = out + 4194304;
    float* ind   = out + 4194305;

    // xb (bf16 x, 8 MB) overlays the quantize region: written by prep, read
    // only by gemm, overwritten by finalize (stream-ordered) -> safe.
    ushort* xb = (ushort*)quant;

    // workspace (20.03 MB)
    char* w = (char*)d_ws;
    ushort* eb16    = (ushort*)(w);               //  4 MB
    uint2*  scratch = (uint2*) (w + 4194304);     // 16 MB  [128][16384]
    float*  e2      = (float*) (w + 20971520);    // 32 KB

    prep_kernel<<<2592, 256, 0, stream>>>(x, embed, xb, eb16, e2);
    gemm_top2_kernel<<<512, 256, 0, stream>>>(xb, eb16, e2, scratch);
    hipMemsetAsync(diff, 0, sizeof(float), stream);
    finalize_kernel<<<256, 256, 0, stream>>>(scratch, x, embed, e2, quant, diff, ind);
}